// Round 19
// baseline (111.108 us; speedup 1.0000x reference)
//
#include <hip/hip_runtime.h>
#include <hip/hip_bf16.h>

// pointconv: density MLP + weight-net + per-point [64x32]x[32x32] + [128x2048] GEMV + BN
// B=16 NP=1024 NS=32 CIN=64 CMID=32 COUT=128. Inputs f32, outputs f32 (bf16 MFMA inside).
// R19 = R12 with fs/mm LDS-ALIASED (both 64KB, temporally disjoint within a cblk):
// LDS 132K -> 64.8K -> 2 blocks/CU (16 waves). Block B's compute hides block A's
// barrier/latency stalls -- the real fix for the 1-block/CU serial-latency plateau
// (R18 showed stage1 front-half IS the ~70us; R13 showed small tiles lose amortization).
// Per cblk: {fs-write; BAR; af->regs; BAR; MFMA + mm-write (same buffer); BAR; stage2; BAR}.

#define NPP 1024

typedef __attribute__((ext_vector_type(8))) short short8;
typedef __attribute__((ext_vector_type(4))) float f32x4;

__device__ __forceinline__ unsigned short f2bf(float x) {
  union { float f; unsigned u; } v; v.f = x;
  unsigned r = v.u + 0x7FFFu + ((v.u >> 16) & 1u);   // RNE
  return (unsigned short)(r >> 16);
}

__device__ __forceinline__ unsigned long long pack4bf(f32x4 v) {
  return (unsigned long long)f2bf(v[0])
       | ((unsigned long long)f2bf(v[1]) << 16)
       | ((unsigned long long)f2bf(v[2]) << 32)
       | ((unsigned long long)f2bf(v[3]) << 48);
}

// ---- k_prep: OWc chunk-major bf16 + output-0 transpose (unchanged) ----
__global__ __launch_bounds__(256) void k_prep(
    const float* __restrict__ out_w, const float* __restrict__ new_xyz,
    unsigned short* __restrict__ owc, float* __restrict__ out0)
{
  int bid = blockIdx.x, t = threadIdx.x;
  if (bid < 128) {
    int gid = bid * 256 + t;           // 32768 = 512 chunks x 64 lanes
    int lane = gid & 63, ci = gid >> 6;
    int hi = ci & 1, tt = (ci >> 1) & 15, cblk = (ci >> 5) & 3, w = ci >> 7;
    int sg = lane >> 4, l15 = lane & 15;
    int o = w*32 + hi*16 + l15;
    int k = tt*2 + (sg >> 1);
    int cbase = cblk*16 + (sg & 1)*8;
    short8 vv;
    #pragma unroll
    for (int j = 0; j < 8; ++j)
      vv[j] = (short)f2bf(out_w[(o*64 + cbase + j)*32 + k]);
    *(short8*)&owc[(size_t)gid * 8] = vv;
  } else {
    int idx = (bid - 128) * 256 + t;   // < 49152
    int b = idx / 3072, r = idx - b*3072, p = r / 3, d = r - p*3;
    out0[idx] = new_xyz[(b*3 + d)*NPP + p];
  }
}

// ---- k_main: one wg = (b, 64-point tile), 8 waves, ~65KB LDS -> 2 blocks/CU ----
struct Smem6 {
  union {
    struct {
      float gxd[64*32*4];            // (x,y,z,d2) per (p,s)   32 KB
      unsigned short wd[16*32*32];   // wd per-wave slices     32 KB
    } ph0;
    unsigned short fsmm[32768];      // fs AND mm (temporally disjoint)  64 KB
  } u;
  float cst[192];
};

__global__ __launch_bounds__(512, 4) void k_main(
    const float* __restrict__ F, const float* __restrict__ GX,
    const float* __restrict__ whw, const float* __restrict__ whb,
    const float* __restrict__ whg, const float* __restrict__ whbeta,
    const float* __restrict__ whm, const float* __restrict__ whv,
    const float* __restrict__ n1w, const float* __restrict__ n1b,
    const float* __restrict__ n1g, const float* __restrict__ n1beta,
    const float* __restrict__ n1m, const float* __restrict__ n1v,
    const float* __restrict__ n2w, const float* __restrict__ n2b,
    const float* __restrict__ n2g, const float* __restrict__ n2beta,
    const float* __restrict__ n2m, const float* __restrict__ n2v,
    const unsigned short* __restrict__ OWc,
    const float* __restrict__ ob, const float* __restrict__ og,
    const float* __restrict__ obeta, const float* __restrict__ om,
    const float* __restrict__ ov,
    float* __restrict__ out1)
{
  __shared__ Smem6 sm;
  int xcd = blockIdx.x & 7, idx = blockIdx.x >> 3;
  int b = xcd*2 + (idx >> 4), pt64 = idx & 15;
  int p0 = pt64 * 64;
  int t = threadIdx.x, w = t >> 6, lane = t & 63;
  int l15 = lane & 15, sg = lane >> 4;

  // staging roles: wave -> (s-octet so, c-half ch); lane -> (q4, c3, jh)
  int so = w & 3, ch = w >> 2;
  int q4 = lane & 3, c3 = (lane >> 2) & 7, jh = (lane >> 5) & 1;
  int c_l = ch*8 + c3, s0 = so*8 + jh*4;
  const float* fsrc0 = &F[((size_t)((b*64 + c_l)*32) + s0)*NPP + p0 + q4*4];

  // ---- phase 0a: gx, density, d2 for all 64 points ----
  int pp8 = t >> 3, si8 = t & 7;
  const float* g = &GX[(size_t)(b*NPP + p0 + pp8)*96 + si8*12];
  float4 f0 = *(const float4*)g;
  float4 f1 = *(const float4*)(g + 4);
  float4 f2 = *(const float4*)(g + 8);

  if (t < 32) {
    float sc = whg[t] * rsqrtf(whv[t] + 1e-5f);
    sm.cst[t]    = whw[t*3+0] * sc;
    sm.cst[32+t] = whw[t*3+1] * sc;
    sm.cst[64+t] = whw[t*3+2] * sc;
    sm.cst[96+t] = (whb[t] - whm[t]) * sc + whbeta[t];
  } else if (t < 48) {
    int i = t - 32;
    float sc = n1g[i] * rsqrtf(n1v[i] + 1e-5f);
    sm.cst[128+i] = n1w[i] * sc;
    sm.cst[144+i] = (n1b[i] - n1m[i]) * sc + n1beta[i];
  } else if (t < 64) {
    int i = t - 48;
    float sc = n2g[0] * rsqrtf(n2v[0] + 1e-5f);
    sm.cst[160+i] = n2w[i] * sc;
    if (i == 0) sm.cst[176] = (n2b[0] - n2m[0]) * sc + n2beta[0];
  }
  __syncthreads();

  {
    float xs[4], ys[4], zs[4], inv[4];
    xs[0]=f0.x; ys[0]=f0.y; zs[0]=f0.z;
    xs[1]=f0.w; ys[1]=f1.x; zs[1]=f1.y;
    xs[2]=f1.z; ys[2]=f1.w; zs[2]=f2.x;
    xs[3]=f2.y; ys[3]=f2.z; zs[3]=f2.w;
    if (si8 == 0) { xs[0]=0.f; ys[0]=0.f; zs[0]=0.f; }   // s=0 zeroed per reference
    float mx = 0.f;
    #pragma unroll
    for (int u = 0; u < 4; ++u) {
      float den = xs[u] + ys[u] + zs[u];
      if (den < 1e-10f) den = 1e-10f;
      inv[u] = 1.0f / den;
      mx = fmaxf(mx, inv[u]);
    }
    #pragma unroll
    for (int m = 1; m < 8; m <<= 1) mx = fmaxf(mx, __shfl_xor(mx, m, 8));
    #pragma unroll
    for (int u = 0; u < 4; ++u) {
      float ds = inv[u] / mx;
      float acc = sm.cst[176];
      #pragma unroll
      for (int i = 0; i < 16; ++i) {
        float d1 = fmaxf(ds * sm.cst[128+i] + sm.cst[144+i], 0.f);
        acc += d1 * sm.cst[160+i];
      }
      float d2 = 1.0f / (1.0f + expf(-acc));
      float4 st = {xs[u], ys[u], zs[u], d2};
      *(float4*)&sm.u.ph0.gxd[(size_t)(pp8*32 + si8*4 + u)*4] = st;
    }
  }
  __syncthreads();

  // ---- phase 0b: wd (intra-wave) + bfr hoist, per pg ----
  const f32x4 z4 = {0,0,0,0};
  int phKh = (lane >> 4) & 1;
  int phPp = w*2 + (lane >> 5);
  int phSi = lane & 15;
  int ppA = w*2, ppB = w*2 + 1;
  int c0 = l15*32 + sg*8;

  short8 bfrA[4][2], bfrB[4][2];       // [pg][kh]
  #pragma unroll
  for (int pg = 0; pg < 4; ++pg) {
    const float4 ga = *(const float4*)&sm.u.ph0.gxd[(size_t)((pg*16 + phPp)*32 + phSi*2)*4];
    const float4 gb = *(const float4*)&sm.u.ph0.gxd[(size_t)((pg*16 + phPp)*32 + phSi*2 + 1)*4];
    #pragma unroll
    for (int ki = 0; ki < 16; ++ki) {
      int k = phKh*16 + ki;
      float a0 = sm.cst[k], a1 = sm.cst[32+k], a2 = sm.cst[64+k], bc = sm.cst[96+k];
      float w0 = fmaxf(ga.x*a0 + ga.y*a1 + ga.z*a2 + bc, 0.f) * ga.w;
      float w1 = fmaxf(gb.x*a0 + gb.y*a1 + gb.z*a2 + bc, 0.f) * gb.w;
      unsigned r = (unsigned)f2bf(w0) | ((unsigned)f2bf(w1) << 16);
      *(unsigned*)&sm.u.ph0.wd[(phPp*32 + k)*32 + phSi*2] = r;
    }
    #pragma unroll
    for (int kh = 0; kh < 2; ++kh) {   // intra-wave RAW on wd
      bfrA[pg][kh] = *(const short8*)&sm.u.ph0.wd[(ppA*32 + kh*16 + l15)*32 + sg*8];
      bfrB[pg][kh] = *(const short8*)&sm.u.ph0.wd[(ppB*32 + kh*16 + l15)*32 + sg*8];
    }
  }
  __syncthreads();   // gxd+wd dead; fsmm may overwrite

  // ---- main loop ----
  int w4 = w & 3, gp0 = (w >> 2) * 2;
  f32x4 acc00 = {0,0,0,0}, acc10 = {0,0,0,0}, acc01 = {0,0,0,0}, acc11 = {0,0,0,0};
  int rowG0 = gp0*16 + l15, rowG1 = (gp0+1)*16 + l15;
  unsigned sw0 = (rowG0 & 15) << 4, sw1 = (rowG1 & 15) << 4;
  const char* bbase0 = (const char*)sm.u.fsmm + rowG0*1024;
  const char* bbase1 = (const char*)sm.u.fsmm + rowG1*1024;
  int fsbase = so*128 + c_l*8 + jh*4;  // u16 idx, + p*512 + jp*2

  #pragma unroll
  for (int cblk = 0; cblk < 4; ++cblk) {
    // fs staging in 2 register-halves (32 VGPR each): load + cvt + swizzled scatter
    #pragma unroll
    for (int half = 0; half < 2; ++half) {
      float4 fvh[4][2];
      const float* fsrc = fsrc0 + (size_t)cblk * 16 * 32 * NPP;
      #pragma unroll
      for (int jj = 0; jj < 4; ++jj)
        #pragma unroll
        for (int qh = 0; qh < 2; ++qh)
          fvh[jj][qh] = *(const float4*)&fsrc[(size_t)jj*NPP + (half*2 + qh)*16];
      #pragma unroll
      for (int qh = 0; qh < 2; ++qh)
        #pragma unroll
        for (int pi = 0; pi < 4; ++pi) {
          int p = (half*2 + qh)*16 + q4*4 + pi;
          unsigned sw = (unsigned)(p & 15) << 3;
          #pragma unroll
          for (int jp = 0; jp < 2; ++jp) {
            unsigned u = (unsigned)f2bf(((const float*)&fvh[jp*2][qh])[pi])
                       | ((unsigned)f2bf(((const float*)&fvh[jp*2+1][qh])[pi]) << 16);
            unsigned fidx = (unsigned)(p*512 + fsbase + jp*2) ^ sw;
            *(unsigned*)&sm.u.fsmm[fidx] = u;
          }
        }
    }
    __syncthreads();

    // af -> registers (must complete before mm overwrites fsmm)
    short8 afA[4], afB[4];
    unsigned swA = (unsigned)(ppA & 15) << 3, swB = (unsigned)(ppB & 15) << 3;
    #pragma unroll
    for (int pg = 0; pg < 4; ++pg) {
      unsigned iA = (unsigned)((pg*16 + ppA)*512 + sg*128 + l15*8) ^ swA;
      unsigned iB = (unsigned)((pg*16 + ppB)*512 + sg*128 + l15*8) ^ swB;
      afA[pg] = *(const short8*)&sm.u.fsmm[iA];
      afB[pg] = *(const short8*)&sm.u.fsmm[iB];
    }
    __syncthreads();   // all af reads done -> fsmm reusable as mm

    // stage 1: MFMA -> mm (XOR-swizzled rows) in the SAME buffer
    #pragma unroll
    for (int pg = 0; pg < 4; ++pg) {
      f32x4 mA0 = __builtin_amdgcn_mfma_f32_16x16x32_bf16(afA[pg], bfrA[pg][0], z4, 0,0,0);
      f32x4 mA1 = __builtin_amdgcn_mfma_f32_16x16x32_bf16(afA[pg], bfrA[pg][1], z4, 0,0,0);
      f32x4 mB0 = __builtin_amdgcn_mfma_f32_16x16x32_bf16(afB[pg], bfrB[pg][0], z4, 0,0,0);
      f32x4 mB1 = __builtin_amdgcn_mfma_f32_16x16x32_bf16(afB[pg], bfrB[pg][1], z4, 0,0,0);
      int rowA = pg*16 + ppA, rowB = pg*16 + ppB;
      unsigned swa = (rowA & 15) << 4, swb = (rowB & 15) << 4;
      char* bA = (char*)sm.u.fsmm + rowA*1024;
      char* bB = (char*)sm.u.fsmm + rowB*1024;
      *(unsigned long long*)(bA + ((c0      ) ^ swa)) = pack4bf(mA0);
      *(unsigned long long*)(bA + ((c0 + 512) ^ swa)) = pack4bf(mA1);
      *(unsigned long long*)(bB + ((c0      ) ^ swb)) = pack4bf(mB0);
      *(unsigned long long*)(bB + ((c0 + 512) ^ swb)) = pack4bf(mB1);
    }
    __syncthreads();

    // stage 2: OWc x mm, accumulate
    {
      const unsigned short* ac = &OWc[(size_t)((w4*4 + cblk)*16)*1024 + lane*8];
      #pragma unroll 8
      for (int tt = 0; tt < 16; ++tt) {
        short8 a0 = *(const short8*)&ac[tt*1024];
        short8 a1 = *(const short8*)&ac[tt*1024 + 512];
        int col = sg*16 + tt*64;
        short8 b0 = *(const short8*)(bbase0 + (col ^ sw0));
        short8 b1 = *(const short8*)(bbase1 + (col ^ sw1));
        acc00 = __builtin_amdgcn_mfma_f32_16x16x32_bf16(a0, b0, acc00, 0,0,0);
        acc10 = __builtin_amdgcn_mfma_f32_16x16x32_bf16(a1, b0, acc10, 0,0,0);
        acc01 = __builtin_amdgcn_mfma_f32_16x16x32_bf16(a0, b1, acc01, 0,0,0);
        acc11 = __builtin_amdgcn_mfma_f32_16x16x32_bf16(a1, b1, acc11, 0,0,0);
      }
    }
    __syncthreads();   // mm consumed; next cblk's fs may overwrite
  }

  // ---- epilogue: +bias, BN, f32 store ----
  #pragma unroll
  for (int hi = 0; hi < 2; ++hi)
    #pragma unroll
    for (int gg = 0; gg < 2; ++gg) {
      f32x4 a = hi ? (gg ? acc11 : acc10) : (gg ? acc01 : acc00);
      #pragma unroll
      for (int r = 0; r < 4; ++r) {
        int o = w4*32 + hi*16 + sg*4 + r;
        float sc = og[o] * rsqrtf(ov[o] + 1e-5f);
        float dd = (ob[o] - om[o]) * sc + obeta[o];
        out1[(size_t)(b*128 + o)*NPP + p0 + (gp0+gg)*16 + l15] = a[r] * sc + dd;
      }
    }
}

extern "C" void kernel_launch(void* const* d_in, const int* in_sizes, int n_in,
                              void* d_out, int out_size, void* d_ws, size_t ws_size,
                              hipStream_t stream) {
  (void)in_sizes; (void)n_in; (void)out_size; (void)ws_size;
  const float* new_xyz = (const float*)d_in[0];
  const float* gxyz    = (const float*)d_in[1];
  const float* gfeat   = (const float*)d_in[2];
  const float* whw     = (const float*)d_in[3];
  const float* whb     = (const float*)d_in[4];
  const float* whg     = (const float*)d_in[5];
  const float* whbeta  = (const float*)d_in[6];
  const float* whm     = (const float*)d_in[7];
  const float* whv     = (const float*)d_in[8];
  const float* n1w     = (const float*)d_in[9];
  const float* n1b     = (const float*)d_in[10];
  const float* n1g     = (const float*)d_in[11];
  const float* n1beta  = (const float*)d_in[12];
  const float* n1m     = (const float*)d_in[13];
  const float* n1v     = (const float*)d_in[14];
  const float* n2w     = (const float*)d_in[15];
  const float* n2b     = (const float*)d_in[16];
  const float* n2g     = (const float*)d_in[17];
  const float* n2beta  = (const float*)d_in[18];
  const float* n2m     = (const float*)d_in[19];
  const float* n2v     = (const float*)d_in[20];
  const float* out_w   = (const float*)d_in[21];
  const float* out_b   = (const float*)d_in[22];
  const float* out_g   = (const float*)d_in[23];
  const float* out_bt  = (const float*)d_in[24];
  const float* out_m   = (const float*)d_in[25];
  const float* out_v   = (const float*)d_in[26];

  unsigned short* owc = (unsigned short*)d_ws;   // 512 KB chunk-major weights
  float* out0 = (float*)d_out;                   // [16][1024][3] f32
  float* out1 = out0 + 16*1024*3;                // [16][128][1024] f32

  hipLaunchKernelGGL(k_prep, dim3(320), dim3(256), 0, stream, out_w, new_xyz, owc, out0);
  hipLaunchKernelGGL(k_main, dim3(256), dim3(512), 0, stream,
      gfeat, gxyz, whw, whb, whg, whbeta, whm, whv,
      n1w, n1b, n1g, n1beta, n1m, n1v,
      n2w, n2b, n2g, n2beta, n2m, n2v,
      owc, out_b, out_g, out_bt, out_m, out_v, out1);
}

// Round 20
// 70.988 us; speedup vs baseline: 1.5652x; 1.5652x over previous
//
#include <hip/hip_runtime.h>
#include <hip/hip_bf16.h>

// pointconv: density MLP + weight-net + per-point [64x32]x[32x32] + [128x2048] GEMV + BN
// B=16 NP=1024 NS=32 CIN=64 CMID=32 COUT=128. Inputs f32, outputs f32 (bf16 MFMA inside).
// FINAL (= R12, best measured: 70.9us clean). Fused single-pass k_main:
//  - F staged per-cblk into p-XOR-swizzled LDS via page-dense reads (fix of the
//    64-page/inst divergence that dominated R3-R8: 137->83us)
//  - OWc chunk-major weights: stage-2 A-loads 1KB line-dense (83->~50us)
//  - fused staging kills the 128MB Fb round-trip (119->70.9us)
//  - mm XOR-swizzled; wd intra-wave; XCD-pinned b.
// R13-R19 structural variants (occupancy, splits, raw barriers, reg-budget attrs)
// all neutral-or-worse with counter-verified causes; this is the practical plateau.

#define NPP 1024

typedef __attribute__((ext_vector_type(8))) short short8;
typedef __attribute__((ext_vector_type(4))) float f32x4;

__device__ __forceinline__ unsigned short f2bf(float x) {
  union { float f; unsigned u; } v; v.f = x;
  unsigned r = v.u + 0x7FFFu + ((v.u >> 16) & 1u);   // RNE
  return (unsigned short)(r >> 16);
}

__device__ __forceinline__ unsigned long long pack4bf(f32x4 v) {
  return (unsigned long long)f2bf(v[0])
       | ((unsigned long long)f2bf(v[1]) << 16)
       | ((unsigned long long)f2bf(v[2]) << 32)
       | ((unsigned long long)f2bf(v[3]) << 48);
}

// ---- k_prep: OWc chunk-major bf16 + output-0 transpose ----
__global__ __launch_bounds__(256) void k_prep(
    const float* __restrict__ out_w, const float* __restrict__ new_xyz,
    unsigned short* __restrict__ owc, float* __restrict__ out0)
{
  int bid = blockIdx.x, t = threadIdx.x;
  if (bid < 128) {
    int gid = bid * 256 + t;           // 32768 = 512 chunks x 64 lanes
    int lane = gid & 63, ci = gid >> 6;
    int hi = ci & 1, tt = (ci >> 1) & 15, cblk = (ci >> 5) & 3, w = ci >> 7;
    int sg = lane >> 4, l15 = lane & 15;
    int o = w*32 + hi*16 + l15;
    int k = tt*2 + (sg >> 1);
    int cbase = cblk*16 + (sg & 1)*8;
    short8 vv;
    #pragma unroll
    for (int j = 0; j < 8; ++j)
      vv[j] = (short)f2bf(out_w[(o*64 + cbase + j)*32 + k]);
    *(short8*)&owc[(size_t)gid * 8] = vv;
  } else {
    int idx = (bid - 128) * 256 + t;   // < 49152
    int b = idx / 3072, r = idx - b*3072, p = r / 3, d = r - p*3;
    out0[idx] = new_xyz[(b*3 + d)*NPP + p];
  }
}

// ---- k_main: one wg = (b, 64-point tile), 8 waves; F staged per-cblk in LDS ----
struct Smem3 {
  union {
    struct {
      float gxd[64*32*4];            // (x,y,z,d2) per (p,s)   32 KB
      unsigned short wd[16*32*32];   // wd per-wave slices     32 KB
    } ph0;
    unsigned short fs[32768];        // per-cblk F tile (swizzled)  64 KB
  } u;
  char mm[64*1024];                  // [p][kflat-this-cblk] swizz  64 KB
  float cst[192];
};

__global__ __launch_bounds__(512, 1) void k_main(
    const float* __restrict__ F, const float* __restrict__ GX,
    const float* __restrict__ whw, const float* __restrict__ whb,
    const float* __restrict__ whg, const float* __restrict__ whbeta,
    const float* __restrict__ whm, const float* __restrict__ whv,
    const float* __restrict__ n1w, const float* __restrict__ n1b,
    const float* __restrict__ n1g, const float* __restrict__ n1beta,
    const float* __restrict__ n1m, const float* __restrict__ n1v,
    const float* __restrict__ n2w, const float* __restrict__ n2b,
    const float* __restrict__ n2g, const float* __restrict__ n2beta,
    const float* __restrict__ n2m, const float* __restrict__ n2v,
    const unsigned short* __restrict__ OWc,
    const float* __restrict__ ob, const float* __restrict__ og,
    const float* __restrict__ obeta, const float* __restrict__ om,
    const float* __restrict__ ov,
    float* __restrict__ out1)
{
  __shared__ Smem3 sm;
  int xcd = blockIdx.x & 7, idx = blockIdx.x >> 3;
  int b = xcd*2 + (idx >> 4), pt64 = idx & 15;
  int p0 = pt64 * 64;
  int t = threadIdx.x, w = t >> 6, lane = t & 63;
  int l15 = lane & 15, sg = lane >> 4;

  // staging roles: wave -> (s-octet so, c-half ch); lane -> (q4, c3, jh)
  int so = w & 3, ch = w >> 2;
  int q4 = lane & 3, c3 = (lane >> 2) & 7, jh = (lane >> 5) & 1;
  int c_l = ch*8 + c3, s0 = so*8 + jh*4;
  const float* fsrc0 = &F[((size_t)((b*64 + c_l)*32) + s0)*NPP + p0 + q4*4];

  // ---- issue cblk0 F loads (hidden under phase 0) ----
  float4 fv[4][4];   // [jj][qg]
  #pragma unroll
  for (int jj = 0; jj < 4; ++jj)
    #pragma unroll
    for (int qg = 0; qg < 4; ++qg)
      fv[jj][qg] = *(const float4*)&fsrc0[(size_t)jj*NPP + qg*16];

  // ---- phase 0a: gx, density, d2 for all 64 points ----
  int pp8 = t >> 3, si8 = t & 7;
  const float* g = &GX[(size_t)(b*NPP + p0 + pp8)*96 + si8*12];
  float4 f0 = *(const float4*)g;
  float4 f1 = *(const float4*)(g + 4);
  float4 f2 = *(const float4*)(g + 8);

  if (t < 32) {
    float sc = whg[t] * rsqrtf(whv[t] + 1e-5f);
    sm.cst[t]    = whw[t*3+0] * sc;
    sm.cst[32+t] = whw[t*3+1] * sc;
    sm.cst[64+t] = whw[t*3+2] * sc;
    sm.cst[96+t] = (whb[t] - whm[t]) * sc + whbeta[t];
  } else if (t < 48) {
    int i = t - 32;
    float sc = n1g[i] * rsqrtf(n1v[i] + 1e-5f);
    sm.cst[128+i] = n1w[i] * sc;
    sm.cst[144+i] = (n1b[i] - n1m[i]) * sc + n1beta[i];
  } else if (t < 64) {
    int i = t - 48;
    float sc = n2g[0] * rsqrtf(n2v[0] + 1e-5f);
    sm.cst[160+i] = n2w[i] * sc;
    if (i == 0) sm.cst[176] = (n2b[0] - n2m[0]) * sc + n2beta[0];
  }
  __syncthreads();

  {
    float xs[4], ys[4], zs[4], inv[4];
    xs[0]=f0.x; ys[0]=f0.y; zs[0]=f0.z;
    xs[1]=f0.w; ys[1]=f1.x; zs[1]=f1.y;
    xs[2]=f1.z; ys[2]=f1.w; zs[2]=f2.x;
    xs[3]=f2.y; ys[3]=f2.z; zs[3]=f2.w;
    if (si8 == 0) { xs[0]=0.f; ys[0]=0.f; zs[0]=0.f; }   // s=0 zeroed per reference
    float mx = 0.f;
    #pragma unroll
    for (int u = 0; u < 4; ++u) {
      float den = xs[u] + ys[u] + zs[u];
      if (den < 1e-10f) den = 1e-10f;
      inv[u] = 1.0f / den;
      mx = fmaxf(mx, inv[u]);
    }
    #pragma unroll
    for (int m = 1; m < 8; m <<= 1) mx = fmaxf(mx, __shfl_xor(mx, m, 8));
    #pragma unroll
    for (int u = 0; u < 4; ++u) {
      float ds = inv[u] / mx;
      float acc = sm.cst[176];
      #pragma unroll
      for (int i = 0; i < 16; ++i) {
        float d1 = fmaxf(ds * sm.cst[128+i] + sm.cst[144+i], 0.f);
        acc += d1 * sm.cst[160+i];
      }
      float d2 = 1.0f / (1.0f + expf(-acc));
      float4 st = {xs[u], ys[u], zs[u], d2};
      *(float4*)&sm.u.ph0.gxd[(size_t)(pp8*32 + si8*4 + u)*4] = st;
    }
  }
  __syncthreads();

  // ---- phase 0b: wd (intra-wave) + bfr hoist, per pg ----
  const f32x4 z4 = {0,0,0,0};
  int phKh = (lane >> 4) & 1;
  int phPp = w*2 + (lane >> 5);
  int phSi = lane & 15;
  int ppA = w*2, ppB = w*2 + 1;
  int c0 = l15*32 + sg*8;

  short8 bfrA[4][2], bfrB[4][2];       // [pg][kh]
  #pragma unroll
  for (int pg = 0; pg < 4; ++pg) {
    const float4 ga = *(const float4*)&sm.u.ph0.gxd[(size_t)((pg*16 + phPp)*32 + phSi*2)*4];
    const float4 gb = *(const float4*)&sm.u.ph0.gxd[(size_t)((pg*16 + phPp)*32 + phSi*2 + 1)*4];
    #pragma unroll
    for (int ki = 0; ki < 16; ++ki) {
      int k = phKh*16 + ki;
      float a0 = sm.cst[k], a1 = sm.cst[32+k], a2 = sm.cst[64+k], bc = sm.cst[96+k];
      float w0 = fmaxf(ga.x*a0 + ga.y*a1 + ga.z*a2 + bc, 0.f) * ga.w;
      float w1 = fmaxf(gb.x*a0 + gb.y*a1 + gb.z*a2 + bc, 0.f) * gb.w;
      unsigned r = (unsigned)f2bf(w0) | ((unsigned)f2bf(w1) << 16);
      *(unsigned*)&sm.u.ph0.wd[(phPp*32 + k)*32 + phSi*2] = r;
    }
    #pragma unroll
    for (int kh = 0; kh < 2; ++kh) {   // intra-wave RAW on wd
      bfrA[pg][kh] = *(const short8*)&sm.u.ph0.wd[(ppA*32 + kh*16 + l15)*32 + sg*8];
      bfrB[pg][kh] = *(const short8*)&sm.u.ph0.wd[(ppB*32 + kh*16 + l15)*32 + sg*8];
    }
  }
  __syncthreads();   // gxd+wd dead; fs may overwrite

  // ---- main loop: per cblk: {fs write; bar; af+stage1 (+issue next F); bar; stage2; bar} ----
  int w4 = w & 3, gp0 = (w >> 2) * 2;
  f32x4 acc00 = {0,0,0,0}, acc10 = {0,0,0,0}, acc01 = {0,0,0,0}, acc11 = {0,0,0,0};
  int rowG0 = gp0*16 + l15, rowG1 = (gp0+1)*16 + l15;
  unsigned sw0 = (rowG0 & 15) << 4, sw1 = (rowG1 & 15) << 4;
  const char* bbase0 = sm.mm + rowG0*1024;
  const char* bbase1 = sm.mm + rowG1*1024;
  int fsbase = so*128 + c_l*8 + jh*4;  // u16 idx, + p*512 + jp*2

  #pragma unroll
  for (int cblk = 0; cblk < 4; ++cblk) {
    // cvt + pack pairs + swizzled LDS scatter (4-way bank max)
    #pragma unroll
    for (int qg = 0; qg < 4; ++qg)
      #pragma unroll
      for (int pi = 0; pi < 4; ++pi) {
        int p = qg*16 + q4*4 + pi;
        unsigned sw = (unsigned)(p & 15) << 3;
        #pragma unroll
        for (int jp = 0; jp < 2; ++jp) {
          unsigned u = (unsigned)f2bf(((const float*)&fv[jp*2][qg])[pi])
                     | ((unsigned)f2bf(((const float*)&fv[jp*2+1][qg])[pi]) << 16);
          unsigned fidx = (unsigned)(p*512 + fsbase + jp*2) ^ sw;
          *(unsigned*)&sm.u.fs[fidx] = u;
        }
      }
    __syncthreads();

    // af loads (1KB-dense b128 with matching XOR)
    short8 afA[4], afB[4];
    unsigned swA = (unsigned)(ppA & 15) << 3, swB = (unsigned)(ppB & 15) << 3;
    #pragma unroll
    for (int pg = 0; pg < 4; ++pg) {
      unsigned iA = (unsigned)((pg*16 + ppA)*512 + sg*128 + l15*8) ^ swA;
      unsigned iB = (unsigned)((pg*16 + ppB)*512 + sg*128 + l15*8) ^ swB;
      afA[pg] = *(const short8*)&sm.u.fs[iA];
      afB[pg] = *(const short8*)&sm.u.fs[iB];
    }
    // issue next cblk's F loads (hidden under stage1/stage2)
    if (cblk < 3) {
      const float* fsrc = fsrc0 + (size_t)(cblk + 1) * 16 * 32 * NPP;
      #pragma unroll
      for (int jj = 0; jj < 4; ++jj)
        #pragma unroll
        for (int qg = 0; qg < 4; ++qg)
          fv[jj][qg] = *(const float4*)&fsrc[(size_t)jj*NPP + qg*16];
    }
    // stage 1: MFMA -> mm (XOR-swizzled rows)
    #pragma unroll
    for (int pg = 0; pg < 4; ++pg) {
      f32x4 mA0 = __builtin_amdgcn_mfma_f32_16x16x32_bf16(afA[pg], bfrA[pg][0], z4, 0,0,0);
      f32x4 mA1 = __builtin_amdgcn_mfma_f32_16x16x32_bf16(afA[pg], bfrA[pg][1], z4, 0,0,0);
      f32x4 mB0 = __builtin_amdgcn_mfma_f32_16x16x32_bf16(afB[pg], bfrB[pg][0], z4, 0,0,0);
      f32x4 mB1 = __builtin_amdgcn_mfma_f32_16x16x32_bf16(afB[pg], bfrB[pg][1], z4, 0,0,0);
      int rowA = pg*16 + ppA, rowB = pg*16 + ppB;
      unsigned swa = (rowA & 15) << 4, swb = (rowB & 15) << 4;
      char* bA = sm.mm + rowA*1024;
      char* bB = sm.mm + rowB*1024;
      *(unsigned long long*)(bA + ((c0      ) ^ swa)) = pack4bf(mA0);
      *(unsigned long long*)(bA + ((c0 + 512) ^ swa)) = pack4bf(mA1);
      *(unsigned long long*)(bB + ((c0      ) ^ swb)) = pack4bf(mB0);
      *(unsigned long long*)(bB + ((c0 + 512) ^ swb)) = pack4bf(mB1);
    }
    __syncthreads();
    // stage 2: OWc x mm, accumulate
    {
      const unsigned short* ac = &OWc[(size_t)((w4*4 + cblk)*16)*1024 + lane*8];
      #pragma unroll 8
      for (int tt = 0; tt < 16; ++tt) {
        short8 a0 = *(const short8*)&ac[tt*1024];
        short8 a1 = *(const short8*)&ac[tt*1024 + 512];
        int col = sg*16 + tt*64;
        short8 b0 = *(const short8*)(bbase0 + (col ^ sw0));
        short8 b1 = *(const short8*)(bbase1 + (col ^ sw1));
        acc00 = __builtin_amdgcn_mfma_f32_16x16x32_bf16(a0, b0, acc00, 0,0,0);
        acc10 = __builtin_amdgcn_mfma_f32_16x16x32_bf16(a1, b0, acc10, 0,0,0);
        acc01 = __builtin_amdgcn_mfma_f32_16x16x32_bf16(a0, b1, acc01, 0,0,0);
        acc11 = __builtin_amdgcn_mfma_f32_16x16x32_bf16(a1, b1, acc11, 0,0,0);
      }
    }
    __syncthreads();
  }

  // ---- epilogue: +bias, BN, f32 store ----
  #pragma unroll
  for (int hi = 0; hi < 2; ++hi)
    #pragma unroll
    for (int gg = 0; gg < 2; ++gg) {
      f32x4 a = hi ? (gg ? acc11 : acc10) : (gg ? acc01 : acc00);
      #pragma unroll
      for (int r = 0; r < 4; ++r) {
        int o = w4*32 + hi*16 + sg*4 + r;
        float sc = og[o] * rsqrtf(ov[o] + 1e-5f);
        float dd = (ob[o] - om[o]) * sc + obeta[o];
        out1[(size_t)(b*128 + o)*NPP + p0 + (gp0+gg)*16 + l15] = a[r] * sc + dd;
      }
    }
}

extern "C" void kernel_launch(void* const* d_in, const int* in_sizes, int n_in,
                              void* d_out, int out_size, void* d_ws, size_t ws_size,
                              hipStream_t stream) {
  (void)in_sizes; (void)n_in; (void)out_size; (void)ws_size;
  const float* new_xyz = (const float*)d_in[0];
  const float* gxyz    = (const float*)d_in[1];
  const float* gfeat   = (const float*)d_in[2];
  const float* whw     = (const float*)d_in[3];
  const float* whb     = (const float*)d_in[4];
  const float* whg     = (const float*)d_in[5];
  const float* whbeta  = (const float*)d_in[6];
  const float* whm     = (const float*)d_in[7];
  const float* whv     = (const float*)d_in[8];
  const float* n1w     = (const float*)d_in[9];
  const float* n1b     = (const float*)d_in[10];
  const float* n1g     = (const float*)d_in[11];
  const float* n1beta  = (const float*)d_in[12];
  const float* n1m     = (const float*)d_in[13];
  const float* n1v     = (const float*)d_in[14];
  const float* n2w     = (const float*)d_in[15];
  const float* n2b     = (const float*)d_in[16];
  const float* n2g     = (const float*)d_in[17];
  const float* n2beta  = (const float*)d_in[18];
  const float* n2m     = (const float*)d_in[19];
  const float* n2v     = (const float*)d_in[20];
  const float* out_w   = (const float*)d_in[21];
  const float* out_b   = (const float*)d_in[22];
  const float* out_g   = (const float*)d_in[23];
  const float* out_bt  = (const float*)d_in[24];
  const float* out_m   = (const float*)d_in[25];
  const float* out_v   = (const float*)d_in[26];

  unsigned short* owc = (unsigned short*)d_ws;   // 512 KB chunk-major weights
  float* out0 = (float*)d_out;                   // [16][1024][3] f32
  float* out1 = out0 + 16*1024*3;                // [16][128][1024] f32

  hipLaunchKernelGGL(k_prep, dim3(320), dim3(256), 0, stream, out_w, new_xyz, owc, out0);
  hipLaunchKernelGGL(k_main, dim3(256), dim3(512), 0, stream,
      gfeat, gxyz, whw, whb, whg, whbeta, whm, whv,
      n1w, n1b, n1g, n1beta, n1m, n1v,
      n2w, n2b, n2g, n2beta, n2m, n2v,
      owc, out_b, out_g, out_bt, out_m, out_v, out1);
}